// Round 2
// baseline (4323.627 us; speedup 1.0000x reference)
//
#include <hip/hip_runtime.h>
#include <cstdint>
#include <cstddef>

#define N_NODES 5000
#define F_IN    7699
#define KP1     7712   // F_IN padded to mult of 32
#define MP      5120   // rows padded to mult of 128
#define E_EDGES 40000
#define EFULL   45000  // E + N self loops
#define HC1     4096   // heads1*ch1
#define N1      8192   // xl|xr concat
#define HC2     1024
#define N2      2048
#define NOUT    128
#define NCHUNK  1024   // GEMM1 column chunk

typedef __bf16 bf16x8 __attribute__((ext_vector_type(8)));
typedef float  f32x4  __attribute__((ext_vector_type(4)));

using as1_ushort = unsigned short __attribute__((address_space(1)));
using as3_ushort = unsigned short __attribute__((address_space(3)));

__device__ __forceinline__ unsigned short f2bf(float f) {
  union { float f; unsigned int u; } v; v.f = f;
  return (unsigned short)((v.u + 0x7fffu + ((v.u >> 16) & 1u)) >> 16);
}
__device__ __forceinline__ float bf2f(unsigned short h) {
  union { unsigned int u; float f; } v; v.u = ((unsigned int)h) << 16;
  return v.f;
}

__device__ __forceinline__ void gload16(const unsigned short* g, unsigned short* l) {
  __builtin_amdgcn_global_load_lds(
      reinterpret_cast<const as1_ushort*>(reinterpret_cast<uintptr_t>(g)),
      reinterpret_cast<as3_ushort*>(reinterpret_cast<uintptr_t>(l)),
      16, 0, 0);
}

// ---------------- conversion kernels ----------------

// x [N_NODES][F_IN] f32 -> hi/lo bf16 [MP][KP1], zero-padded
__global__ void k_split_x(const float* __restrict__ x, unsigned short* __restrict__ hi,
                          unsigned short* __restrict__ lo) {
  long long i = (long long)blockIdx.x * 256 + threadIdx.x;
  const long long total = (long long)MP * KP1;
  if (i >= total) return;
  int r = (int)(i / KP1), c = (int)(i % KP1);
  float v = (r < N_NODES && c < F_IN) ? x[(long long)r * F_IN + c] : 0.f;
  unsigned short h = f2bf(v);
  hi[i] = h;
  lo[i] = f2bf(v - bf2f(h));
}

// W [K][N_src] f32, cols [c0, c0+32*gridDim.y) -> hi/lo [rowOffset+n][Kp] bf16 transposed
__global__ void k_transpose_split(const float* __restrict__ W,
                                  unsigned short* __restrict__ hi, unsigned short* __restrict__ lo,
                                  int K, int N_src, int c0, int Kp, int rowOffset) {
  __shared__ float tile[32][33];
  int k0 = blockIdx.x * 32, n0 = blockIdx.y * 32;
  int tx = threadIdx.x, ty = threadIdx.y;
  #pragma unroll
  for (int i = ty; i < 32; i += 8) {
    int k = k0 + i;
    tile[i][tx] = (k < K) ? W[(size_t)k * N_src + c0 + n0 + tx] : 0.f;
  }
  __syncthreads();
  #pragma unroll
  for (int i = ty; i < 32; i += 8) {
    int n = n0 + i, k = k0 + tx;
    if (k < Kp) {
      float v = tile[tx][i];
      unsigned short h = f2bf(v);
      size_t o = (size_t)(rowOffset + n) * Kp + k;
      hi[o] = h;
      lo[o] = f2bf(v - bf2f(h));
    }
  }
}

// ---------------- split-bf16 GEMM ----------------
// C[gr][gc] = sum_k (Ahi+Alo)[gr][k] * (Bhi+Blo)[gc][k]  (3-term: hh + lh + hl)
// 128x128 tile, BK=32, 4 waves 2x2, each wave 4x4 frags of 16x16x32, 48 MFMA/K-step.

__global__ __launch_bounds__(256) void k_gemm_split(
    const unsigned short* __restrict__ Ahi, const unsigned short* __restrict__ Alo,
    const unsigned short* __restrict__ Bhi, const unsigned short* __restrict__ Blo,
    float* __restrict__ C, const float* __restrict__ bias0, const float* __restrict__ bias1,
    int halfN, int M, int ldC, int Kp)
{
  __shared__ unsigned short AhS[128 * 32];
  __shared__ unsigned short AlS[128 * 32];
  __shared__ unsigned short BhS[128 * 32];
  __shared__ unsigned short BlS[128 * 32];
  const int tid = threadIdx.x;
  const int lane = tid & 63;
  const int w = tid >> 6;
  const int wm = w >> 1, wn = w & 1;
  const int bn = blockIdx.x, bm = blockIdx.y;

  f32x4 acc[4][4] = {};

  const int rA0 = bm * 128 + 32 * w + (lane >> 2);
  const int rB0 = bn * 128 + 32 * w + (lane >> 2);
  const int kk = (lane & 3) * 8;
  unsigned short* lAh  = &AhS[(2 * w) * 512];
  unsigned short* lAh2 = &AhS[(2 * w + 1) * 512];
  unsigned short* lAl  = &AlS[(2 * w) * 512];
  unsigned short* lAl2 = &AlS[(2 * w + 1) * 512];
  unsigned short* lBh  = &BhS[(2 * w) * 512];
  unsigned short* lBh2 = &BhS[(2 * w + 1) * 512];
  unsigned short* lBl  = &BlS[(2 * w) * 512];
  unsigned short* lBl2 = &BlS[(2 * w + 1) * 512];

  const int KT = Kp >> 5;
  const int rrd = lane & 15;
  const int krd = (lane >> 4) * 8;

  for (int kt = 0; kt < KT; ++kt) {
    const int kb = kt * 32 + kk;
    const size_t a0 = (size_t)rA0 * Kp + kb, a1 = (size_t)(rA0 + 16) * Kp + kb;
    const size_t b0 = (size_t)rB0 * Kp + kb, b1 = (size_t)(rB0 + 16) * Kp + kb;
    gload16(Ahi + a0, lAh);  gload16(Ahi + a1, lAh2);
    gload16(Alo + a0, lAl);  gload16(Alo + a1, lAl2);
    gload16(Bhi + b0, lBh);  gload16(Bhi + b1, lBh2);
    gload16(Blo + b0, lBl);  gload16(Blo + b1, lBl2);
    __syncthreads();
    bf16x8 ah[4], al[4], bh[4], bl[4];
    #pragma unroll
    for (int i = 0; i < 4; ++i) {
      const int ro = (wm * 64 + i * 16 + rrd) * 32 + krd;
      ah[i] = *(const bf16x8*)&AhS[ro];
      al[i] = *(const bf16x8*)&AlS[ro];
    }
    #pragma unroll
    for (int j = 0; j < 4; ++j) {
      const int ro = (wn * 64 + j * 16 + rrd) * 32 + krd;
      bh[j] = *(const bf16x8*)&BhS[ro];
      bl[j] = *(const bf16x8*)&BlS[ro];
    }
    #pragma unroll
    for (int i = 0; i < 4; ++i)
      #pragma unroll
      for (int j = 0; j < 4; ++j) {
        acc[i][j] = __builtin_amdgcn_mfma_f32_16x16x32_bf16(ah[i], bh[j], acc[i][j], 0, 0, 0);
        acc[i][j] = __builtin_amdgcn_mfma_f32_16x16x32_bf16(al[i], bh[j], acc[i][j], 0, 0, 0);
        acc[i][j] = __builtin_amdgcn_mfma_f32_16x16x32_bf16(ah[i], bl[j], acc[i][j], 0, 0, 0);
      }
    __syncthreads();
  }

  // C/D layout: col=lane&15, row=(lane>>4)*4+reg
  const int rowb = bm * 128 + wm * 64 + (lane >> 4) * 4;
  const int colb = wn * 64 + (lane & 15) + bn * 128;
  #pragma unroll
  for (int i = 0; i < 4; ++i) {
    #pragma unroll
    for (int j = 0; j < 4; ++j) {
      int gc = colb + j * 16;
      float bv = (gc < halfN) ? bias0[gc] : bias1[gc - halfN];
      #pragma unroll
      for (int r = 0; r < 4; ++r) {
        int gr = rowb + i * 16 + r;
        if (gr < M) C[(size_t)gr * ldC + gc] = acc[i][j][r] + bv;
      }
    }
  }
}

// ---------------- graph prep ----------------

__global__ void k_deg(const int* __restrict__ dst, const float* __restrict__ ea,
                      float* __restrict__ deg, float* __restrict__ lattr, int E) {
  int e = blockIdx.x * 256 + threadIdx.x;
  if (e >= E) return;
  int d = dst[e];
  atomicAdd(&deg[d], 1.f);
  atomicAdd(&lattr[d * 3 + 0], ea[e * 3 + 0]);
  atomicAdd(&lattr[d * 3 + 1], ea[e * 3 + 1]);
  atomicAdd(&lattr[d * 3 + 2], ea[e * 3 + 2]);
}

__global__ void k_lattr_fin(float* __restrict__ lattr, const float* __restrict__ deg, int n) {
  int i = blockIdx.x * 256 + threadIdx.x;
  if (i >= n) return;
  float dv = fmaxf(deg[i], 1.f);
  lattr[i * 3 + 0] /= dv; lattr[i * 3 + 1] /= dv; lattr[i * 3 + 2] /= dv;
}

__global__ void k_eafull(const float* __restrict__ ea, const float* __restrict__ lattr,
                         float* __restrict__ eaf, int E, int n) {
  int e = blockIdx.x * 256 + threadIdx.x;
  if (e >= E + n) return;
  const float* s = (e < E) ? &ea[(size_t)e * 3] : &lattr[(size_t)(e - E) * 3];
  eaf[e * 3 + 0] = s[0]; eaf[e * 3 + 1] = s[1]; eaf[e * 3 + 2] = s[2];
}

__global__ void k_count(const int* __restrict__ dst, int* __restrict__ cnt, int E, int n) {
  int e = blockIdx.x * 256 + threadIdx.x;
  if (e >= E + n) return;
  int d = (e < E) ? dst[e] : (e - E);
  atomicAdd(&cnt[d], 1);
}

__global__ void k_scan(const int* __restrict__ cnt, int* __restrict__ rowptr, int n) {
  int lane = threadIdx.x;   // 64 threads, 1 block
  int run = 0;
  for (int base = 0; base < n; base += 64) {
    int i = base + lane;
    int v = (i < n) ? cnt[i] : 0;
    #pragma unroll
    for (int off = 1; off < 64; off <<= 1) {
      int t = __shfl_up(v, off, 64);
      if (lane >= off) v += t;
    }
    if (i < n) rowptr[i + 1] = run + v;
    run += __shfl(v, 63, 64);
  }
  if (lane == 0) rowptr[0] = 0;
}

__global__ void k_fill(const int* __restrict__ dst, const int* __restrict__ rowptr,
                       int* __restrict__ fillc, int* __restrict__ elist, int E, int n) {
  int e = blockIdx.x * 256 + threadIdx.x;
  if (e >= E + n) return;
  int d = (e < E) ? dst[e] : (e - E);
  int pos = rowptr[d] + atomicAdd(&fillc[d], 1);
  elist[pos] = e;
}

// ---------------- GATv2 edge phase (f32) ----------------

template <int H, int ITERS>
__global__ __launch_bounds__(256) void k_logit(
    const float* __restrict__ xl, const float* __restrict__ xr, int strideX,
    const float* __restrict__ eaf, const float* __restrict__ We, const float* __restrict__ att,
    const int* __restrict__ src, const int* __restrict__ dst, int E,
    float* __restrict__ logit)
{
  const int e = blockIdx.x;
  const int tid = threadIdx.x;
  int s, d;
  if (e < E) { s = src[e]; d = dst[e]; } else { s = e - E; d = s; }
  const float ea0 = eaf[e * 3 + 0], ea1 = eaf[e * 3 + 1], ea2 = eaf[e * 3 + 2];
  constexpr int HC = ITERS * 256;
  const float* rl = xl + (size_t)s * strideX;
  const float* rr = xr + (size_t)d * strideX;
  float acc[H];
  #pragma unroll
  for (int h = 0; h < H; ++h) acc[h] = 0.f;
  #pragma unroll
  for (int i = 0; i < ITERS; ++i) {
    int hc = tid + (i << 8);
    float v = rl[hc] + rr[hc] + ea0 * We[hc] + ea1 * We[HC + hc] + ea2 * We[2 * HC + hc];
    v = (v > 0.f) ? v : 0.2f * v;
    acc[i >> 2] += v * att[hc];
  }
  __shared__ float red[H][4];
  const int lane = tid & 63, wv = tid >> 6;
  #pragma unroll
  for (int h = 0; h < H; ++h) {
    float v = acc[h];
    #pragma unroll
    for (int off = 32; off > 0; off >>= 1) v += __shfl_down(v, off, 64);
    if (lane == 0) red[h][wv] = v;
  }
  __syncthreads();
  if (tid < H)
    logit[(size_t)e * H + tid] = red[tid][0] + red[tid][1] + red[tid][2] + red[tid][3];
}

template <int H>
__global__ void k_stats(const float* __restrict__ logit, const int* __restrict__ rowptr,
                        const int* __restrict__ elist, float* __restrict__ mb, float* __restrict__ db)
{
  const int n = blockIdx.x;
  const int lane = threadIdx.x;   // 64
  const int start = rowptr[n], end = rowptr[n + 1];
  #pragma unroll
  for (int h = 0; h < H; ++h) {
    float m = -1e30f;
    for (int p = start + lane; p < end; p += 64)
      m = fmaxf(m, logit[(size_t)elist[p] * H + h]);
    #pragma unroll
    for (int off = 32; off > 0; off >>= 1) m = fmaxf(m, __shfl_down(m, off, 64));
    m = __shfl(m, 0, 64);
    float sum = 0.f;
    for (int p = start + lane; p < end; p += 64)
      sum += __expf(logit[(size_t)elist[p] * H + h] - m);
    #pragma unroll
    for (int off = 32; off > 0; off >>= 1) sum += __shfl_down(sum, off, 64);
    if (lane == 0) { mb[n * H + h] = m; db[n * H + h] = sum; }
  }
}

// out = sum_e alpha[e][h] * xl[src(e)][hc] + bias[hc], stored as bf16 hi/lo pair
template <int H, int ITERS>
__global__ __launch_bounds__(256) void k_agg(
    const float* __restrict__ xl, int strideX,
    const int* __restrict__ rowptr, const int* __restrict__ elist, const int* __restrict__ src,
    const float* __restrict__ logit, const float* __restrict__ mb, const float* __restrict__ db,
    const float* __restrict__ bias,
    unsigned short* __restrict__ ohi, unsigned short* __restrict__ olo, int strideO, int E)
{
  const int n = blockIdx.x;
  const int tid = threadIdx.x;
  float acc[ITERS];
  #pragma unroll
  for (int i = 0; i < ITERS; ++i) acc[i] = 0.f;
  const int start = rowptr[n], end = rowptr[n + 1];
  float mloc[H], dloc[H];
  #pragma unroll
  for (int h = 0; h < H; ++h) { mloc[h] = mb[n * H + h]; dloc[h] = db[n * H + h] + 1e-16f; }
  for (int p = start; p < end; ++p) {
    const int e = elist[p];
    const int s = (e < E) ? src[e] : (e - E);
    float al[H];
    #pragma unroll
    for (int h = 0; h < H; ++h)
      al[h] = __expf(logit[(size_t)e * H + h] - mloc[h]) / dloc[h];
    const float* row = xl + (size_t)s * strideX;
    #pragma unroll
    for (int i = 0; i < ITERS; ++i)
      acc[i] += al[i >> 2] * row[tid + (i << 8)];
  }
  #pragma unroll
  for (int i = 0; i < ITERS; ++i) {
    int hc = tid + (i << 8);
    float v = acc[i] + bias[hc];
    unsigned short h = f2bf(v);
    size_t o = (size_t)n * strideO + hc;
    ohi[o] = h;
    olo[o] = f2bf(v - bf2f(h));
  }
}

// ---------------- launch ----------------

extern "C" void kernel_launch(void* const* d_in, const int* in_sizes, int n_in,
                              void* d_out, int out_size, void* d_ws, size_t ws_size,
                              hipStream_t stream) {
  const float* x    = (const float*)d_in[0];
  const int*   eidx = (const int*)d_in[1];
  const float* eattr= (const float*)d_in[2];
  const float* W1l  = (const float*)d_in[3];
  const float* b1l  = (const float*)d_in[4];
  const float* W1r  = (const float*)d_in[5];
  const float* b1r  = (const float*)d_in[6];
  const float* W1e  = (const float*)d_in[7];
  const float* att1 = (const float*)d_in[8];
  const float* bias1= (const float*)d_in[9];
  const float* W2l  = (const float*)d_in[10];
  const float* b2l  = (const float*)d_in[11];
  const float* W2r  = (const float*)d_in[12];
  const float* b2r  = (const float*)d_in[13];
  const float* W2e  = (const float*)d_in[14];
  const float* att2 = (const float*)d_in[15];
  const float* bias2= (const float*)d_in[16];
  const float* Wlin = (const float*)d_in[17];
  const float* blin = (const float*)d_in[18];
  float* out = (float*)d_out;

  char* ws = (char*)d_ws;
  const int* srcp = eidx;
  const int* dstp = eidx + E_EDGES;

  auto alignup = [](size_t v) { return (v + 255) & ~(size_t)255; };

  // ---- layout (~357 MB, within proven 371 MB budget) ----
  const size_t oXHI = 0;                                  // Ahi [MP][KP1] bf16: 79 MB
  const size_t oXLO = oXHI + (size_t)MP * KP1 * 2;        // Alo: 79 MB
  const size_t oXLR = oXLO + (size_t)MP * KP1 * 2;        // xl|xr f32 [5000][8192]: 164 MB
  const size_t oBHI = oXLR + (size_t)N_NODES * N1 * 4;    // B chunk hi: 16.8 MB (2048*4096*2)
  const size_t oBLO = oBHI + (size_t)2048 * 4096 * 2;     // B chunk lo: 16.8 MB
  const size_t oS   = oBLO + (size_t)2048 * 4096 * 2;
  const size_t oLATTR = alignup(oS);
  const size_t oDEG   = alignup(oLATTR + (size_t)N_NODES * 3 * 4);
  const size_t oEAF   = alignup(oDEG + (size_t)N_NODES * 4);
  const size_t oCNT   = alignup(oEAF + (size_t)EFULL * 3 * 4);
  const size_t oROW   = alignup(oCNT + (size_t)N_NODES * 4);
  const size_t oFILL  = alignup(oROW + (size_t)(N_NODES + 1) * 4);
  const size_t oELIST = alignup(oFILL + (size_t)N_NODES * 4);
  const size_t oLOGIT = alignup(oELIST + (size_t)EFULL * 4);
  const size_t oMB    = alignup(oLOGIT + (size_t)EFULL * 4 * 4);
  const size_t oDB    = alignup(oMB + (size_t)N_NODES * 4 * 4);
  const size_t oEND   = alignup(oDB + (size_t)N_NODES * 4 * 4);
  if (ws_size < oEND) return;

  // overlays
  const size_t oH1HI = oXHI;                           // [MP][4096] bf16: 42 MB (in 79)
  const size_t oH1LO = oXLO;                           // 42 MB (in 79)
  const size_t oXLR2 = oXLR;                           // f32 [5000][2048]: 41 MB (in 164)
  const size_t oH2HI = oXLR + 64ull * 1024 * 1024;     // [MP][1024] bf16: 10.5 MB
  const size_t oH2LO = oXLR + 80ull * 1024 * 1024;     // 10.5 MB

  unsigned short* XHI  = (unsigned short*)(ws + oXHI);
  unsigned short* XLO  = (unsigned short*)(ws + oXLO);
  float*          XLR  = (float*)(ws + oXLR);
  unsigned short* BHI  = (unsigned short*)(ws + oBHI);
  unsigned short* BLO  = (unsigned short*)(ws + oBLO);
  float*          LATTR= (float*)(ws + oLATTR);
  float*          DEG  = (float*)(ws + oDEG);
  float*          EAF  = (float*)(ws + oEAF);
  int*            CNT  = (int*)(ws + oCNT);
  int*            ROWP = (int*)(ws + oROW);
  int*            FILLC= (int*)(ws + oFILL);
  int*            ELIST= (int*)(ws + oELIST);
  float*          LOGIT= (float*)(ws + oLOGIT);
  float*          MB   = (float*)(ws + oMB);
  float*          DB   = (float*)(ws + oDB);
  unsigned short* H1HI = (unsigned short*)(ws + oH1HI);
  unsigned short* H1LO = (unsigned short*)(ws + oH1LO);
  float*          XLR2 = (float*)(ws + oXLR2);
  unsigned short* H2HI = (unsigned short*)(ws + oH2HI);
  unsigned short* H2LO = (unsigned short*)(ws + oH2LO);

  hipMemsetAsync(ws + oDEG,   0, (size_t)N_NODES * 4, stream);
  hipMemsetAsync(ws + oLATTR, 0, (size_t)N_NODES * 3 * 4, stream);
  hipMemsetAsync(ws + oCNT,   0, (size_t)N_NODES * 4, stream);
  hipMemsetAsync(ws + oFILL,  0, (size_t)N_NODES * 4, stream);

  const dim3 tb(32, 8);
  const int gE  = (E_EDGES + 255) / 256;
  const int gEF = (EFULL + 255) / 256;
  const int gN  = (N_NODES + 255) / 256;

  // ---- graph structure ----
  k_deg<<<gE, 256, 0, stream>>>(dstp, eattr, DEG, LATTR, E_EDGES);
  k_lattr_fin<<<gN, 256, 0, stream>>>(LATTR, DEG, N_NODES);
  k_eafull<<<gEF, 256, 0, stream>>>(eattr, LATTR, EAF, E_EDGES, N_NODES);
  k_count<<<gEF, 256, 0, stream>>>(dstp, CNT, E_EDGES, N_NODES);
  k_scan<<<1, 64, 0, stream>>>(CNT, ROWP, N_NODES);
  k_fill<<<gEF, 256, 0, stream>>>(dstp, ROWP, FILLC, ELIST, E_EDGES, N_NODES);

  // ---- layer 1: split x, chunked split GEMM (8 x 1024 cols) ----
  {
    long long total = (long long)MP * KP1;
    k_split_x<<<(int)((total + 255) / 256), 256, 0, stream>>>(x, XHI, XLO);
  }
  for (int c = 0; c < 8; ++c) {
    const float* Wsrc = (c < 4) ? W1l : W1r;
    const float* bsrc = (c < 4) ? (b1l + (c & 3) * NCHUNK) : (b1r + (c & 3) * NCHUNK);
    int c0 = (c & 3) * NCHUNK;
    k_transpose_split<<<dim3(KP1 / 32, NCHUNK / 32), tb, 0, stream>>>(
        Wsrc, BHI, BLO, F_IN, HC1, c0, KP1, 0);
    k_gemm_split<<<dim3(NCHUNK / 128, MP / 128), 256, 0, stream>>>(
        XHI, XLO, BHI, BLO, XLR + c * NCHUNK, bsrc, bsrc, NCHUNK, N_NODES, N1, KP1);
  }

  // ---- layer 1 attention + aggregation ----
  k_logit<4, 16><<<EFULL, 256, 0, stream>>>(XLR, XLR + HC1, N1, EAF, W1e, att1, srcp, dstp, E_EDGES, LOGIT);
  k_stats<4><<<N_NODES, 64, 0, stream>>>(LOGIT, ROWP, ELIST, MB, DB);
  k_agg<4, 16><<<N_NODES, 256, 0, stream>>>(XLR, N1, ROWP, ELIST, srcp, LOGIT, MB, DB, bias1,
                                            H1HI, H1LO, HC1, E_EDGES);

  // ---- layer 2 ----
  k_transpose_split<<<dim3(HC1 / 32, HC2 / 32), tb, 0, stream>>>(W2l, BHI, BLO, HC1, HC2, 0, HC1, 0);
  k_transpose_split<<<dim3(HC1 / 32, HC2 / 32), tb, 0, stream>>>(W2r, BHI, BLO, HC1, HC2, 0, HC1, HC2);
  k_gemm_split<<<dim3(N2 / 128, MP / 128), 256, 0, stream>>>(
      H1HI, H1LO, BHI, BLO, XLR2, b2l, b2r, HC2, N_NODES, N2, HC1);

  k_logit<1, 4><<<EFULL, 256, 0, stream>>>(XLR2, XLR2 + HC2, N2, EAF, W2e, att2, srcp, dstp, E_EDGES, LOGIT);
  k_stats<1><<<N_NODES, 64, 0, stream>>>(LOGIT, ROWP, ELIST, MB, DB);
  k_agg<1, 4><<<N_NODES, 256, 0, stream>>>(XLR2, N2, ROWP, ELIST, srcp, LOGIT, MB, DB, bias2,
                                           H2HI, H2LO, HC2, E_EDGES);

  // ---- final linear: [5000][1024] x [1024][128] -> d_out ----
  k_transpose_split<<<dim3(HC2 / 32, NOUT / 32), tb, 0, stream>>>(Wlin, BHI, BLO, HC2, NOUT, 0, HC2, 0);
  k_gemm_split<<<dim3(NOUT / 128, MP / 128), 256, 0, stream>>>(
      H2HI, H2LO, BHI, BLO, out, blin, blin, NOUT, N_NODES, NOUT, HC2);
}

// Round 3
// 3132.357 us; speedup vs baseline: 1.3803x; 1.3803x over previous
//
#include <hip/hip_runtime.h>
#include <cstdint>
#include <cstddef>

#define N_NODES 5000
#define F_IN    7699
#define KP1     7712   // F_IN padded to mult of 32
#define MP      5120   // rows padded to mult of 128
#define E_EDGES 40000
#define EFULL   45000  // E + N self loops
#define HC1     4096   // heads1*ch1
#define N1      8192   // xl|xr concat
#define HC2     1024
#define N2      2048
#define NOUT    128

#define S16(r) ((((r) ^ ((r) >> 2))) & 3)

typedef __bf16 bf16x8 __attribute__((ext_vector_type(8)));
typedef float  f32x4  __attribute__((ext_vector_type(4)));
typedef unsigned int u32x4 __attribute__((ext_vector_type(4)));

using as1_uchar = unsigned char __attribute__((address_space(1)));
using as3_uchar = unsigned char __attribute__((address_space(3)));

__device__ __forceinline__ unsigned short f2bf(float f) {
  union { float f; unsigned int u; } v; v.f = f;
  return (unsigned short)((v.u + 0x7fffu + ((v.u >> 16) & 1u)) >> 16);
}
__device__ __forceinline__ float bf2f(unsigned short h) {
  union { unsigned int u; float f; } v; v.u = ((unsigned int)h) << 16;
  return v.f;
}

__device__ __forceinline__ void gload16(const void* g, void* l) {
  __builtin_amdgcn_global_load_lds(
      reinterpret_cast<const as1_uchar*>(reinterpret_cast<uintptr_t>(g)),
      reinterpret_cast<as3_uchar*>(reinterpret_cast<uintptr_t>(l)),
      16, 0, 0);
}

// ---------------- conversion ----------------

// x [N_NODES][F_IN] f32 -> hi/lo bf16 [MP][KP1], zero-padded
__global__ void k_split_x(const float* __restrict__ x, unsigned short* __restrict__ hi,
                          unsigned short* __restrict__ lo) {
  long long i = (long long)blockIdx.x * 256 + threadIdx.x;
  const long long total = (long long)MP * KP1;
  if (i >= total) return;
  int r = (int)(i / KP1), c = (int)(i % KP1);
  float v = (r < N_NODES && c < F_IN) ? x[(long long)r * F_IN + c] : 0.f;
  unsigned short h = f2bf(v);
  hi[i] = h;
  lo[i] = f2bf(v - bf2f(h));
}

// ---------------- streamed split-bf16 GEMM ----------------
// C[gr][gc] = sum_k (Ahi+Alo)[gr][k]*(Bhi+Blo)[k][gc], B split computed on the fly
// from f32 source [K][N]. 128x128 tile, BK=32, 4 waves 2x2, 48 MFMA/K-step.
// LDS: A hi/lo 8KB+8KB staged by global_load_lds (source-kpart-swizzled);
// B: 16KB f32 tile staged linearly -> regs -> cvt_pk hi/lo -> ds_write back
// into the same 16KB as transposed [n][k] hi|lo (kpart-swizzled).

__global__ __launch_bounds__(256) void k_gemm_stream(
    const unsigned short* __restrict__ Ahi, const unsigned short* __restrict__ Alo,
    const float* __restrict__ B0, const float* __restrict__ B1, int ldB, int halfNB,
    float* __restrict__ C, const float* __restrict__ bias0, const float* __restrict__ bias1,
    int halfN, int M, int ldC, int Kp, int Klim, const float* __restrict__ zbuf, int gx)
{
  __shared__ __align__(16) unsigned short AhS[4096];
  __shared__ __align__(16) unsigned short AlS[4096];
  __shared__ __align__(16) float BfS[4096];
  unsigned short* BtH = reinterpret_cast<unsigned short*>(BfS);
  unsigned short* BtL = BtH + 4096;

  const int tid = threadIdx.x;
  const int lane = tid & 63;
  const int w = tid >> 6;
  const int wm = w >> 1, wn = w & 1;

  // bijective XCD-chunked swizzle (gridDim.x divisible by 8)
  const int chunk = gridDim.x >> 3;
  const int wg = (blockIdx.x & 7) * chunk + (blockIdx.x >> 3);
  const int bm = wg / gx, bn = wg % gx;

  const float* Bp = (bn < halfNB) ? B0 : B1;
  const int cb = ((bn < halfNB) ? bn : (bn - halfNB)) * 128;

  f32x4 acc[4][4] = {};

  // A staging: per wave, 2 buffers of 16 rows; lane -> (relrow=lane>>2, kpart=lane&3).
  // Source kpart pre-swizzled so that swizzled reads see linear data.
  const int relr = lane >> 2;
  const int kkA = (((lane & 3) ^ S16(relr)) << 3);
  const int rA0 = bm * 128 + 32 * w + relr;
  unsigned short* lAh  = &AhS[(2 * w) * 512];
  unsigned short* lAh2 = &AhS[(2 * w + 1) * 512];
  unsigned short* lAl  = &AlS[(2 * w) * 512];
  unsigned short* lAl2 = &AlS[(2 * w + 1) * 512];

  // B f32 staging: issue q covers k = q*8 + 2*w + (lane>>5), cols (lane&31)*4..+3
  const int kB = 2 * w + (lane >> 5);
  const int nB = (lane & 31) << 2;
  char* bfc = reinterpret_cast<char*>(BfS);

  // convert: thread -> col cc, k range [kh, kh+16)
  const int cc = tid & 127;
  const int kh = (tid >> 7) << 4;
  const int scv = S16(cc & 15);
  const int kp0 = kh >> 3;

  // frag reads: row = base + rrd, kpart = (lane>>4) ^ S16(rrd)
  const int rrd = lane & 15;
  const int kpr = (((lane >> 4) ^ S16(rrd)) << 3);

  const int KT = Kp >> 5;
  for (int kt = 0; kt < KT; ++kt) {
    const int kb = kt * 32;
    const size_t a0 = (size_t)rA0 * Kp + kb + kkA;
    const size_t a1 = a0 + (size_t)16 * Kp;
    gload16(Ahi + a0, lAh);  gload16(Ahi + a1, lAh2);
    gload16(Alo + a0, lAl);  gload16(Alo + a1, lAl2);
    #pragma unroll
    for (int q = 0; q < 4; ++q) {
      int kg = kb + q * 8 + kB;
      const float* sp = (kg < Klim) ? (Bp + (size_t)kg * ldB + cb + nB) : zbuf;
      gload16(sp, bfc + q * 4096 + w * 1024);
    }
    __syncthreads();

    // read B f32 tile into regs (conflict-free: bank = cc%32), read A frags
    float bv[16];
    #pragma unroll
    for (int j = 0; j < 16; ++j) bv[j] = BfS[(kh + j) * 128 + cc];
    bf16x8 ah[4], al[4];
    #pragma unroll
    for (int i = 0; i < 4; ++i) {
      const int ro = (wm * 64 + i * 16 + rrd) * 32 + kpr;
      ah[i] = *(const bf16x8*)&AhS[ro];
      al[i] = *(const bf16x8*)&AlS[ro];
    }
    __syncthreads();

    // convert + write transposed hi/lo (RNE via v_cvt_pk_bf16_f32)
    #pragma unroll
    for (int u = 0; u < 2; ++u) {
      u32x4 hv, lv;
      #pragma unroll
      for (int m = 0; m < 4; ++m) {
        float a0f = bv[8 * u + 2 * m], a1f = bv[8 * u + 2 * m + 1];
        unsigned int ph, pl;
        asm("v_cvt_pk_bf16_f32 %0, %1, %2" : "=v"(ph) : "v"(a0f), "v"(a1f));
        union { unsigned int u; float f; } h0, h1;
        h0.u = ph << 16; h1.u = ph & 0xFFFF0000u;
        float l0 = a0f - h0.f, l1 = a1f - h1.f;
        asm("v_cvt_pk_bf16_f32 %0, %1, %2" : "=v"(pl) : "v"(l0), "v"(l1));
        hv[m] = ph; lv[m] = pl;
      }
      const int off = cc * 32 + (((kp0 + u) ^ scv) << 3);
      *(u32x4*)&BtH[off] = hv;
      *(u32x4*)&BtL[off] = lv;
    }
    __syncthreads();

    bf16x8 bh[4], bl[4];
    #pragma unroll
    for (int j = 0; j < 4; ++j) {
      const int ro = (wn * 64 + j * 16 + rrd) * 32 + kpr;
      bh[j] = *(const bf16x8*)&BtH[ro];
      bl[j] = *(const bf16x8*)&BtL[ro];
    }
    #pragma unroll
    for (int i = 0; i < 4; ++i)
      #pragma unroll
      for (int j = 0; j < 4; ++j) {
        acc[i][j] = __builtin_amdgcn_mfma_f32_16x16x32_bf16(ah[i], bh[j], acc[i][j], 0, 0, 0);
        acc[i][j] = __builtin_amdgcn_mfma_f32_16x16x32_bf16(al[i], bh[j], acc[i][j], 0, 0, 0);
        acc[i][j] = __builtin_amdgcn_mfma_f32_16x16x32_bf16(ah[i], bl[j], acc[i][j], 0, 0, 0);
      }
    __syncthreads();
  }

  // epilogue: C/D layout col=lane&15, row=(lane>>4)*4+reg
  const int rowb = bm * 128 + wm * 64 + (lane >> 4) * 4;
  const int colb = bn * 128 + wn * 64 + (lane & 15);
  #pragma unroll
  for (int i = 0; i < 4; ++i) {
    #pragma unroll
    for (int j = 0; j < 4; ++j) {
      int gc = colb + j * 16;
      float bvv = (gc < halfN) ? bias0[gc] : bias1[gc - halfN];
      #pragma unroll
      for (int r = 0; r < 4; ++r) {
        int gr = rowb + i * 16 + r;
        if (gr < M) C[(size_t)gr * ldC + gc] = acc[i][j][r] + bvv;
      }
    }
  }
}

// ---------------- graph prep ----------------

__global__ void k_deg(const int* __restrict__ dst, const float* __restrict__ ea,
                      float* __restrict__ deg, float* __restrict__ lattr, int E) {
  int e = blockIdx.x * 256 + threadIdx.x;
  if (e >= E) return;
  int d = dst[e];
  atomicAdd(&deg[d], 1.f);
  atomicAdd(&lattr[d * 3 + 0], ea[e * 3 + 0]);
  atomicAdd(&lattr[d * 3 + 1], ea[e * 3 + 1]);
  atomicAdd(&lattr[d * 3 + 2], ea[e * 3 + 2]);
}

__global__ void k_lattr_fin(float* __restrict__ lattr, const float* __restrict__ deg, int n) {
  int i = blockIdx.x * 256 + threadIdx.x;
  if (i >= n) return;
  float dv = fmaxf(deg[i], 1.f);
  lattr[i * 3 + 0] /= dv; lattr[i * 3 + 1] /= dv; lattr[i * 3 + 2] /= dv;
}

__global__ void k_eafull(const float* __restrict__ ea, const float* __restrict__ lattr,
                         float* __restrict__ eaf, int E, int n) {
  int e = blockIdx.x * 256 + threadIdx.x;
  if (e >= E + n) return;
  const float* s = (e < E) ? &ea[(size_t)e * 3] : &lattr[(size_t)(e - E) * 3];
  eaf[e * 3 + 0] = s[0]; eaf[e * 3 + 1] = s[1]; eaf[e * 3 + 2] = s[2];
}

__global__ void k_count(const int* __restrict__ dst, int* __restrict__ cnt, int E, int n) {
  int e = blockIdx.x * 256 + threadIdx.x;
  if (e >= E + n) return;
  int d = (e < E) ? dst[e] : (e - E);
  atomicAdd(&cnt[d], 1);
}

__global__ void k_scan(const int* __restrict__ cnt, int* __restrict__ rowptr, int n) {
  int lane = threadIdx.x;   // 64 threads, 1 block
  int run = 0;
  for (int base = 0; base < n; base += 64) {
    int i = base + lane;
    int v = (i < n) ? cnt[i] : 0;
    #pragma unroll
    for (int off = 1; off < 64; off <<= 1) {
      int t = __shfl_up(v, off, 64);
      if (lane >= off) v += t;
    }
    if (i < n) rowptr[i + 1] = run + v;
    run += __shfl(v, 63, 64);
  }
  if (lane == 0) rowptr[0] = 0;
}

__global__ void k_fill(const int* __restrict__ dst, const int* __restrict__ rowptr,
                       int* __restrict__ fillc, int* __restrict__ elist, int E, int n) {
  int e = blockIdx.x * 256 + threadIdx.x;
  if (e >= E + n) return;
  int d = (e < E) ? dst[e] : (e - E);
  int pos = rowptr[d] + atomicAdd(&fillc[d], 1);
  elist[pos] = e;
}

// ---------------- GATv2 edge phase (f32) ----------------

template <int H, int ITERS>
__global__ __launch_bounds__(256) void k_logit(
    const float* __restrict__ xl, const float* __restrict__ xr, int strideX,
    const float* __restrict__ eaf, const float* __restrict__ We, const float* __restrict__ att,
    const int* __restrict__ src, const int* __restrict__ dst, int E,
    float* __restrict__ logit)
{
  const int e = blockIdx.x;
  const int tid = threadIdx.x;
  int s, d;
  if (e < E) { s = src[e]; d = dst[e]; } else { s = e - E; d = s; }
  const float ea0 = eaf[e * 3 + 0], ea1 = eaf[e * 3 + 1], ea2 = eaf[e * 3 + 2];
  constexpr int HC = ITERS * 256;
  const float* rl = xl + (size_t)s * strideX;
  const float* rr = xr + (size_t)d * strideX;
  float acc[H];
  #pragma unroll
  for (int h = 0; h < H; ++h) acc[h] = 0.f;
  #pragma unroll
  for (int i = 0; i < ITERS; ++i) {
    int hc = tid + (i << 8);
    float v = rl[hc] + rr[hc] + ea0 * We[hc] + ea1 * We[HC + hc] + ea2 * We[2 * HC + hc];
    v = (v > 0.f) ? v : 0.2f * v;
    acc[i >> 2] += v * att[hc];
  }
  __shared__ float red[H][4];
  const int lane = tid & 63, wv = tid >> 6;
  #pragma unroll
  for (int h = 0; h < H; ++h) {
    float v = acc[h];
    #pragma unroll
    for (int off = 32; off > 0; off >>= 1) v += __shfl_down(v, off, 64);
    if (lane == 0) red[h][wv] = v;
  }
  __syncthreads();
  if (tid < H)
    logit[(size_t)e * H + tid] = red[tid][0] + red[tid][1] + red[tid][2] + red[tid][3];
}

template <int H>
__global__ void k_stats(const float* __restrict__ logit, const int* __restrict__ rowptr,
                        const int* __restrict__ elist, float* __restrict__ mb, float* __restrict__ db)
{
  const int n = blockIdx.x;
  const int lane = threadIdx.x;   // 64
  const int start = rowptr[n], end = rowptr[n + 1];
  #pragma unroll
  for (int h = 0; h < H; ++h) {
    float m = -1e30f;
    for (int p = start + lane; p < end; p += 64)
      m = fmaxf(m, logit[(size_t)elist[p] * H + h]);
    #pragma unroll
    for (int off = 32; off > 0; off >>= 1) m = fmaxf(m, __shfl_down(m, off, 64));
    m = __shfl(m, 0, 64);
    float sum = 0.f;
    for (int p = start + lane; p < end; p += 64)
      sum += __expf(logit[(size_t)elist[p] * H + h] - m);
    #pragma unroll
    for (int off = 32; off > 0; off >>= 1) sum += __shfl_down(sum, off, 64);
    if (lane == 0) { mb[n * H + h] = m; db[n * H + h] = sum; }
  }
}

// out = sum_e alpha[e][h] * xl[src(e)][hc] + bias[hc], stored as bf16 hi/lo pair
template <int H, int ITERS>
__global__ __launch_bounds__(256) void k_agg(
    const float* __restrict__ xl, int strideX,
    const int* __restrict__ rowptr, const int* __restrict__ elist, const int* __restrict__ src,
    const float* __restrict__ logit, const float* __restrict__ mb, const float* __restrict__ db,
    const float* __restrict__ bias,
    unsigned short* __restrict__ ohi, unsigned short* __restrict__ olo, int strideO, int E)
{
  const int n = blockIdx.x;
  const int tid = threadIdx.x;
  float acc[ITERS];
  #pragma unroll
  for (int i = 0; i < ITERS; ++i) acc[i] = 0.f;
  const int start = rowptr[n], end = rowptr[n + 1];
  float mloc[H], dloc[H];
  #pragma unroll
  for (int h = 0; h < H; ++h) { mloc[h] = mb[n * H + h]; dloc[h] = db[n * H + h] + 1e-16f; }
  for (int p = start; p < end; ++p) {
    const int e = elist[p];
    const int s = (e < E) ? src[e] : (e - E);
    float al[H];
    #pragma unroll
    for (int h = 0; h < H; ++h)
      al[h] = __expf(logit[(size_t)e * H + h] - mloc[h]) / dloc[h];
    const float* row = xl + (size_t)s * strideX;
    #pragma unroll
    for (int i = 0; i < ITERS; ++i)
      acc[i] += al[i >> 2] * row[tid + (i << 8)];
  }
  #pragma unroll
  for (int i = 0; i < ITERS; ++i) {
    int hc = tid + (i << 8);
    float v = acc[i] + bias[hc];
    unsigned short h = f2bf(v);
    size_t o = (size_t)n * strideO + hc;
    ohi[o] = h;
    olo[o] = f2bf(v - bf2f(h));
  }
}

// ---------------- launch ----------------

extern "C" void kernel_launch(void* const* d_in, const int* in_sizes, int n_in,
                              void* d_out, int out_size, void* d_ws, size_t ws_size,
                              hipStream_t stream) {
  const float* x    = (const float*)d_in[0];
  const int*   eidx = (const int*)d_in[1];
  const float* eattr= (const float*)d_in[2];
  const float* W1l  = (const float*)d_in[3];
  const float* b1l  = (const float*)d_in[4];
  const float* W1r  = (const float*)d_in[5];
  const float* b1r  = (const float*)d_in[6];
  const float* W1e  = (const float*)d_in[7];
  const float* att1 = (const float*)d_in[8];
  const float* bias1= (const float*)d_in[9];
  const float* W2l  = (const float*)d_in[10];
  const float* b2l  = (const float*)d_in[11];
  const float* W2r  = (const float*)d_in[12];
  const float* b2r  = (const float*)d_in[13];
  const float* W2e  = (const float*)d_in[14];
  const float* att2 = (const float*)d_in[15];
  const float* bias2= (const float*)d_in[16];
  const float* Wlin = (const float*)d_in[17];
  const float* blin = (const float*)d_in[18];
  float* out = (float*)d_out;

  char* ws = (char*)d_ws;
  const int* srcp = eidx;
  const int* dstp = eidx + E_EDGES;

  auto alignup = [](size_t v) { return (v + 255) & ~(size_t)255; };

  // ---- layout (~325 MB) ----
  const size_t oXHI = 0;                                  // 79 MB
  const size_t oXLO = oXHI + (size_t)MP * KP1 * 2;        // 79 MB
  const size_t oXLR = oXLO + (size_t)MP * KP1 * 2;        // xl|xr f32 [5000][8192]: 164 MB
  const size_t oS   = oXLR + (size_t)N_NODES * N1 * 4;
  const size_t oLATTR = alignup(oS);
  const size_t oDEG   = alignup(oLATTR + (size_t)N_NODES * 3 * 4);
  const size_t oEAF   = alignup(oDEG + (size_t)N_NODES * 4);
  const size_t oCNT   = alignup(oEAF + (size_t)EFULL * 3 * 4);
  const size_t oROW   = alignup(oCNT + (size_t)N_NODES * 4);
  const size_t oFILL  = alignup(oROW + (size_t)(N_NODES + 1) * 4);
  const size_t oELIST = alignup(oFILL + (size_t)N_NODES * 4);
  const size_t oLOGIT = alignup(oELIST + (size_t)EFULL * 4);
  const size_t oMB    = alignup(oLOGIT + (size_t)EFULL * 4 * 4);
  const size_t oDB    = alignup(oMB + (size_t)N_NODES * 4 * 4);
  const size_t oZBUF  = alignup(oDB + (size_t)N_NODES * 4 * 4);
  const size_t oEND   = alignup(oZBUF + 256);
  if (ws_size < oEND) return;

  // overlays (regions free by the time these are written)
  const size_t oH1HI = oXHI;                           // [MP][4096] bf16: 42 MB (in 79)
  const size_t oH1LO = oXLO;                           // 42 MB (in 79)
  const size_t oXLR2 = oXLR;                           // f32 [5000][2048]: 41 MB (in 164)
  const size_t oH2HI = oXLR + 64ull * 1024 * 1024;     // [MP][1024] bf16: 10.5 MB
  const size_t oH2LO = oXLR + 80ull * 1024 * 1024;     // 10.5 MB

  unsigned short* XHI  = (unsigned short*)(ws + oXHI);
  unsigned short* XLO  = (unsigned short*)(ws + oXLO);
  float*          XLR  = (float*)(ws + oXLR);
  float*          LATTR= (float*)(ws + oLATTR);
  float*          DEG  = (float*)(ws + oDEG);
  float*          EAF  = (float*)(ws + oEAF);
  int*            CNT  = (int*)(ws + oCNT);
  int*            ROWP = (int*)(ws + oROW);
  int*            FILLC= (int*)(ws + oFILL);
  int*            ELIST= (int*)(ws + oELIST);
  float*          LOGIT= (float*)(ws + oLOGIT);
  float*          MB   = (float*)(ws + oMB);
  float*          DB   = (float*)(ws + oDB);
  float*          ZBUF = (float*)(ws + oZBUF);
  unsigned short* H1HI = (unsigned short*)(ws + oH1HI);
  unsigned short* H1LO = (unsigned short*)(ws + oH1LO);
  float*          XLR2 = (float*)(ws + oXLR2);
  unsigned short* H2HI = (unsigned short*)(ws + oH2HI);
  unsigned short* H2LO = (unsigned short*)(ws + oH2LO);

  hipMemsetAsync(ws + oDEG,   0, (size_t)N_NODES * 4, stream);
  hipMemsetAsync(ws + oLATTR, 0, (size_t)N_NODES * 3 * 4, stream);
  hipMemsetAsync(ws + oCNT,   0, (size_t)N_NODES * 4, stream);
  hipMemsetAsync(ws + oFILL,  0, (size_t)N_NODES * 4, stream);
  hipMemsetAsync(ws + oZBUF,  0, 256, stream);

  const int gE  = (E_EDGES + 255) / 256;
  const int gEF = (EFULL + 255) / 256;
  const int gN  = (N_NODES + 255) / 256;

  // ---- graph structure ----
  k_deg<<<gE, 256, 0, stream>>>(dstp, eattr, DEG, LATTR, E_EDGES);
  k_lattr_fin<<<gN, 256, 0, stream>>>(LATTR, DEG, N_NODES);
  k_eafull<<<gEF, 256, 0, stream>>>(eattr, LATTR, EAF, E_EDGES, N_NODES);
  k_count<<<gEF, 256, 0, stream>>>(dstp, CNT, E_EDGES, N_NODES);
  k_scan<<<1, 64, 0, stream>>>(CNT, ROWP, N_NODES);
  k_fill<<<gEF, 256, 0, stream>>>(dstp, ROWP, FILLC, ELIST, E_EDGES, N_NODES);

  // ---- layer 1: split x, single streamed GEMM (N=8192) ----
  {
    long long total = (long long)MP * KP1;
    k_split_x<<<(int)((total + 255) / 256), 256, 0, stream>>>(x, XHI, XLO);
  }
  k_gemm_stream<<<64 * (MP / 128), 256, 0, stream>>>(
      XHI, XLO, W1l, W1r, HC1, 32,
      XLR, b1l, b1r, HC1, N_NODES, N1, KP1, F_IN, ZBUF, 64);

  // ---- layer 1 attention + aggregation ----
  k_logit<4, 16><<<EFULL, 256, 0, stream>>>(XLR, XLR + HC1, N1, EAF, W1e, att1, srcp, dstp, E_EDGES, LOGIT);
  k_stats<4><<<N_NODES, 64, 0, stream>>>(LOGIT, ROWP, ELIST, MB, DB);
  k_agg<4, 16><<<N_NODES, 256, 0, stream>>>(XLR, N1, ROWP, ELIST, srcp, LOGIT, MB, DB, bias1,
                                            H1HI, H1LO, HC1, E_EDGES);

  // ---- layer 2 ----
  k_gemm_stream<<<16 * (MP / 128), 256, 0, stream>>>(
      H1HI, H1LO, W2l, W2r, HC2, 8,
      XLR2, b2l, b2r, HC2, N_NODES, N2, HC1, HC1, ZBUF, 16);

  k_logit<1, 4><<<EFULL, 256, 0, stream>>>(XLR2, XLR2 + HC2, N2, EAF, W2e, att2, srcp, dstp, E_EDGES, LOGIT);
  k_stats<1><<<N_NODES, 64, 0, stream>>>(LOGIT, ROWP, ELIST, MB, DB);
  k_agg<1, 4><<<N_NODES, 256, 0, stream>>>(XLR2, N2, ROWP, ELIST, srcp, LOGIT, MB, DB, bias2,
                                           H2HI, H2LO, HC2, E_EDGES);

  // ---- final linear ----
  k_gemm_stream<<<1 * (MP / 128), 256, 0, stream>>>(
      H2HI, H2LO, Wlin, Wlin, NOUT, 1,
      out, blin, blin, NOUT, N_NODES, NOUT, HC2, HC2, ZBUF, 1);
}

// Round 4
// 3068.591 us; speedup vs baseline: 1.4090x; 1.0208x over previous
//
#include <hip/hip_runtime.h>
#include <cstdint>
#include <cstddef>

#define N_NODES 5000
#define F_IN    7699
#define KP1     7712   // F_IN padded to mult of 32
#define KT1     241    // KP1/32
#define MP      5120   // rows padded to mult of 128
#define E_EDGES 40000
#define EFULL   45000  // E + N self loops
#define HC1     4096   // heads1*ch1
#define N1      8192   // xl|xr concat
#define HC2     1024
#define N2      2048
#define NOUT    128

typedef __bf16 bf16x8 __attribute__((ext_vector_type(8)));
typedef float  f32x4  __attribute__((ext_vector_type(4)));
typedef unsigned int u32x4 __attribute__((ext_vector_type(4)));
typedef unsigned short u16x8 __attribute__((ext_vector_type(8)));

using as1_uchar = unsigned char __attribute__((address_space(1)));
using as3_uchar = unsigned char __attribute__((address_space(3)));

__device__ __forceinline__ unsigned short f2bf(float f) {
  union { float f; unsigned int u; } v; v.f = f;
  return (unsigned short)((v.u + 0x7fffu + ((v.u >> 16) & 1u)) >> 16);
}
__device__ __forceinline__ float bf2f(unsigned short h) {
  union { unsigned int u; float f; } v; v.u = ((unsigned int)h) << 16;
  return v.f;
}

__device__ __forceinline__ void gload16(const void* g, void* l) {
  __builtin_amdgcn_global_load_lds(
      reinterpret_cast<const as1_uchar*>(reinterpret_cast<uintptr_t>(g)),
      reinterpret_cast<as3_uchar*>(reinterpret_cast<uintptr_t>(l)),
      16, 0, 0);
}

// Brick layout for GEMM-A operands (global, matches LDS chunk-plane exactly):
// element (row r, k c) -> ((r>>7)*KT + (c>>5))*4096 + ((c>>3)&3)*1024 + (r&127)*8 + (c&7)
// Each (row-tile, k-step) brick is 8KB, staged as 8 contiguous 1KB gload_lds issues.

// ---------------- conversion: x -> hi/lo bricks ----------------

__global__ void k_split_x(const float* __restrict__ x, unsigned short* __restrict__ hi,
                          unsigned short* __restrict__ lo) {
  const int C8 = KP1 / 8;                       // 964
  int ci = blockIdx.x * 256 + threadIdx.x;
  if (ci >= MP * C8) return;
  int r = ci / C8, c8 = ci % C8;
  int c = c8 * 8;
  u16x8 hb, lb;
  #pragma unroll
  for (int j = 0; j < 8; ++j) {
    float v = 0.f;
    if (r < N_NODES && (c + j) < F_IN) v = x[(size_t)r * F_IN + c + j];
    unsigned short h = f2bf(v);
    hb[j] = h; lb[j] = f2bf(v - bf2f(h));
  }
  size_t off = ((size_t)((r >> 7) * KT1 + (c >> 5)) * 4 + ((c >> 3) & 3)) * 1024 + (r & 127) * 8;
  *(u16x8*)&hi[off] = hb;
  *(u16x8*)&lo[off] = lb;
}

// ---------------- split-bf16 GEMM, brick-A, streamed-B ----------------
// C[r][c] = sum_k (Ahi+Alo)[r][k]*(Bhi+Blo)[k][c]; B split from f32 on the fly.
// 128x128 tile, BK=32, 4 waves 2x2, 48 MFMA/wave/K-step, 2 barriers/K-step.
// A: gload_lds of pre-bricked global (contiguous 1KB, conflict-free frag reads).
// B: global->reg (coalesced, 1 K-step ahead) -> cvt_pk hi/lo -> chunk-plane ds_write.

__global__ __launch_bounds__(256, 3) void k_gemm_bs(
    const unsigned short* __restrict__ Ahi, const unsigned short* __restrict__ Alo,
    const float* __restrict__ B0, const float* __restrict__ B1, int ldB, int halfNB,
    float* __restrict__ C, const float* __restrict__ bias0, const float* __restrict__ bias1,
    int halfN, int M, int ldC, int KT, int Klim, int gm)
{
  __shared__ __align__(16) unsigned short AhS[4096];
  __shared__ __align__(16) unsigned short AlS[4096];
  __shared__ __align__(16) unsigned short BhS[4096];
  __shared__ __align__(16) unsigned short BlS[4096];

  const int tid = threadIdx.x;
  const int lane = tid & 63;
  const int w = tid >> 6;
  const int wm = w >> 1, wn = w & 1;

  // bijective XCD swizzle; column-major (consecutive blocks share the B panel)
  const int chunkg = gridDim.x >> 3;
  const int wg = (blockIdx.x & 7) * chunkg + (blockIdx.x >> 3);
  const int bm = wg % gm, bn = wg / gm;

  const float* Bp = (bn < halfNB) ? B0 : B1;
  const int cb = ((bn < halfNB) ? bn : bn - halfNB) * 128;

  f32x4 acc[4][4] = {};

  const unsigned short* AbH = Ahi + (size_t)bm * KT * 4096;
  const unsigned short* AbL = Alo + (size_t)bm * KT * 4096;
  const int sOff = w * 1024 + lane * 8;   // ushort offset of this lane within brick

  const int ccB = tid & 127;              // B column owned by this thread
  const int kB0 = (tid >> 7) * 16;        // B k sub-range base
  const int c0  = (tid >> 7) * 2;         // first chunk-plane for B write

  const int fr = lane & 15;
  const int fchunk = (lane >> 4) * 1024;

  float breg[16];

  auto loadB = [&](int kt) {
    #pragma unroll
    for (int j = 0; j < 16; ++j) {
      int kg = kt * 32 + kB0 + j;
      breg[j] = (kg < Klim) ? Bp[(size_t)kg * ldB + cb + ccB] : 0.f;
    }
  };
  auto stageA = [&](int kt) {
    const unsigned short* bh = AbH + (size_t)kt * 4096 + sOff;
    const unsigned short* bl = AbL + (size_t)kt * 4096 + sOff;
    gload16(bh,       &AhS[w * 1024]);
    gload16(bh + 512, &AhS[w * 1024 + 512]);
    gload16(bl,       &AlS[w * 1024]);
    gload16(bl + 512, &AlS[w * 1024 + 512]);
  };
  auto convB = [&]() {
    #pragma unroll
    for (int u = 0; u < 2; ++u) {
      u32x4 hv, lv;
      #pragma unroll
      for (int m = 0; m < 4; ++m) {
        float a0f = breg[8 * u + 2 * m], a1f = breg[8 * u + 2 * m + 1];
        unsigned int ph, pl;
        asm("v_cvt_pk_bf16_f32 %0, %1, %2" : "=v"(ph) : "v"(a0f), "v"(a1f));
        union { unsigned int u_; float f; } h0, h1;
        h0.u_ = ph << 16; h1.u_ = ph & 0xFFFF0000u;
        float l0 = a0f - h0.f, l1 = a1f - h1.f;
        asm("v_cvt_pk_bf16_f32 %0, %1, %2" : "=v"(pl) : "v"(l0), "v"(l1));
        hv[m] = ph; lv[m] = pl;
      }
      const int off = (c0 + u) * 1024 + ccB * 8;
      *(u32x4*)&BhS[off] = hv;
      *(u32x4*)&BlS[off] = lv;
    }
  };

  loadB(0);
  stageA(0);
  convB();
  loadB(1);
  __syncthreads();

  for (int kt = 0; kt < KT; ++kt) {
    bf16x8 ah[4], al[4];
    #pragma unroll
    for (int i = 0; i < 4; ++i) {
      const int ro = fchunk + (wm * 64 + i * 16 + fr) * 8;
      ah[i] = *(const bf16x8*)&AhS[ro];
      al[i] = *(const bf16x8*)&AlS[ro];
    }
    #pragma unroll
    for (int j = 0; j < 4; ++j) {
      const int ro = fchunk + (wn * 64 + j * 16 + fr) * 8;
      bf16x8 bh = *(const bf16x8*)&BhS[ro];
      bf16x8 bl = *(const bf16x8*)&BlS[ro];
      #pragma unroll
      for (int i = 0; i < 4; ++i) {
        acc[i][j] = __builtin_amdgcn_mfma_f32_16x16x32_bf16(ah[i], bh, acc[i][j], 0, 0, 0);
        acc[i][j] = __builtin_amdgcn_mfma_f32_16x16x32_bf16(al[i], bh, acc[i][j], 0, 0, 0);
        acc[i][j] = __builtin_amdgcn_mfma_f32_16x16x32_bf16(ah[i], bl, acc[i][j], 0, 0, 0);
      }
    }
    if (kt + 1 < KT) {
      __syncthreads();      // frag reads done -> safe to overwrite LDS
      stageA(kt + 1);
      convB();              // breg holds tile kt+1
      loadB(kt + 2);        // Klim guard zeroes past-end
      __syncthreads();      // staging visible
    }
  }

  // epilogue: C/D layout col=lane&15, row=(lane>>4)*4+reg
  const int rowb = bm * 128 + wm * 64 + (lane >> 4) * 4;
  const int colb = bn * 128 + wn * 64 + (lane & 15);
  #pragma unroll
  for (int i = 0; i < 4; ++i) {
    #pragma unroll
    for (int j = 0; j < 4; ++j) {
      int gc = colb + j * 16;
      float bvv = (gc < halfN) ? bias0[gc] : bias1[gc - halfN];
      #pragma unroll
      for (int r = 0; r < 4; ++r) {
        int gr = rowb + i * 16 + r;
        if (gr < M) C[(size_t)gr * ldC + gc] = acc[i][j][r] + bvv;
      }
    }
  }
}

// ---------------- graph prep ----------------

__global__ void k_deg(const int* __restrict__ dst, const float* __restrict__ ea,
                      float* __restrict__ deg, float* __restrict__ lattr, int E) {
  int e = blockIdx.x * 256 + threadIdx.x;
  if (e >= E) return;
  int d = dst[e];
  atomicAdd(&deg[d], 1.f);
  atomicAdd(&lattr[d * 3 + 0], ea[e * 3 + 0]);
  atomicAdd(&lattr[d * 3 + 1], ea[e * 3 + 1]);
  atomicAdd(&lattr[d * 3 + 2], ea[e * 3 + 2]);
}

__global__ void k_lattr_fin(float* __restrict__ lattr, const float* __restrict__ deg, int n) {
  int i = blockIdx.x * 256 + threadIdx.x;
  if (i >= n) return;
  float dv = fmaxf(deg[i], 1.f);
  lattr[i * 3 + 0] /= dv; lattr[i * 3 + 1] /= dv; lattr[i * 3 + 2] /= dv;
}

__global__ void k_eafull(const float* __restrict__ ea, const float* __restrict__ lattr,
                         float* __restrict__ eaf, int E, int n) {
  int e = blockIdx.x * 256 + threadIdx.x;
  if (e >= E + n) return;
  const float* s = (e < E) ? &ea[(size_t)e * 3] : &lattr[(size_t)(e - E) * 3];
  eaf[e * 3 + 0] = s[0]; eaf[e * 3 + 1] = s[1]; eaf[e * 3 + 2] = s[2];
}

__global__ void k_count(const int* __restrict__ dst, int* __restrict__ cnt, int E, int n) {
  int e = blockIdx.x * 256 + threadIdx.x;
  if (e >= E + n) return;
  int d = (e < E) ? dst[e] : (e - E);
  atomicAdd(&cnt[d], 1);
}

__global__ void k_scan(const int* __restrict__ cnt, int* __restrict__ rowptr, int n) {
  int lane = threadIdx.x;   // 64 threads, 1 block
  int run = 0;
  for (int base = 0; base < n; base += 64) {
    int i = base + lane;
    int v = (i < n) ? cnt[i] : 0;
    #pragma unroll
    for (int off = 1; off < 64; off <<= 1) {
      int t = __shfl_up(v, off, 64);
      if (lane >= off) v += t;
    }
    if (i < n) rowptr[i + 1] = run + v;
    run += __shfl(v, 63, 64);
  }
  if (lane == 0) rowptr[0] = 0;
}

__global__ void k_fill(const int* __restrict__ dst, const int* __restrict__ rowptr,
                       int* __restrict__ fillc, int* __restrict__ elist, int E, int n) {
  int e = blockIdx.x * 256 + threadIdx.x;
  if (e >= E + n) return;
  int d = (e < E) ? dst[e] : (e - E);
  int pos = rowptr[d] + atomicAdd(&fillc[d], 1);
  elist[pos] = e;
}

// ---------------- GATv2 edge phase (f32) ----------------

template <int H, int ITERS>
__global__ __launch_bounds__(256) void k_logit(
    const float* __restrict__ xl, const float* __restrict__ xr, int strideX,
    const float* __restrict__ eaf, const float* __restrict__ We, const float* __restrict__ att,
    const int* __restrict__ src, const int* __restrict__ dst, int E,
    float* __restrict__ logit)
{
  const int e = blockIdx.x;
  const int tid = threadIdx.x;
  int s, d;
  if (e < E) { s = src[e]; d = dst[e]; } else { s = e - E; d = s; }
  const float ea0 = eaf[e * 3 + 0], ea1 = eaf[e * 3 + 1], ea2 = eaf[e * 3 + 2];
  constexpr int HC = ITERS * 256;
  const float* rl = xl + (size_t)s * strideX;
  const float* rr = xr + (size_t)d * strideX;
  float acc[H];
  #pragma unroll
  for (int h = 0; h < H; ++h) acc[h] = 0.f;
  #pragma unroll
  for (int i = 0; i < ITERS; ++i) {
    int hc = tid + (i << 8);
    float v = rl[hc] + rr[hc] + ea0 * We[hc] + ea1 * We[HC + hc] + ea2 * We[2 * HC + hc];
    v = (v > 0.f) ? v : 0.2f * v;
    acc[i >> 2] += v * att[hc];
  }
  __shared__ float red[H][4];
  const int lane = tid & 63, wv = tid >> 6;
  #pragma unroll
  for (int h = 0; h < H; ++h) {
    float v = acc[h];
    #pragma unroll
    for (int off = 32; off > 0; off >>= 1) v += __shfl_down(v, off, 64);
    if (lane == 0) red[h][wv] = v;
  }
  __syncthreads();
  if (tid < H)
    logit[(size_t)e * H + tid] = red[tid][0] + red[tid][1] + red[tid][2] + red[tid][3];
}

template <int H>
__global__ void k_stats(const float* __restrict__ logit, const int* __restrict__ rowptr,
                        const int* __restrict__ elist, float* __restrict__ mb, float* __restrict__ db)
{
  const int n = blockIdx.x;
  const int lane = threadIdx.x;   // 64
  const int start = rowptr[n], end = rowptr[n + 1];
  #pragma unroll
  for (int h = 0; h < H; ++h) {
    float m = -1e30f;
    for (int p = start + lane; p < end; p += 64)
      m = fmaxf(m, logit[(size_t)elist[p] * H + h]);
    #pragma unroll
    for (int off = 32; off > 0; off >>= 1) m = fmaxf(m, __shfl_down(m, off, 64));
    m = __shfl(m, 0, 64);
    float sum = 0.f;
    for (int p = start + lane; p < end; p += 64)
      sum += __expf(logit[(size_t)elist[p] * H + h] - m);
    #pragma unroll
    for (int off = 32; off > 0; off >>= 1) sum += __shfl_down(sum, off, 64);
    if (lane == 0) { mb[n * H + h] = m; db[n * H + h] = sum; }
  }
}

// out[n][hc] = sum_e alpha*xl[src][hc] + bias, stored as hi/lo BRICKS (GEMM-A layout).
// thread owns 8-contiguous-hc chunks: c8 = tid + q*256 (guarded)
template <int H, int NC8, int KTo>
__global__ __launch_bounds__(256) void k_agg(
    const float* __restrict__ xl, int strideX,
    const int* __restrict__ rowptr, const int* __restrict__ elist, const int* __restrict__ src,
    const float* __restrict__ logit, const float* __restrict__ mb, const float* __restrict__ db,
    const float* __restrict__ bias,
    unsigned short* __restrict__ ohi, unsigned short* __restrict__ olo, int E)
{
  const int n = blockIdx.x;
  const int tid = threadIdx.x;
  constexpr int HC = H * 1024;
  float acc[NC8][8];
  #pragma unroll
  for (int q = 0; q < NC8; ++q)
    #pragma unroll
    for (int j = 0; j < 8; ++j) acc[q][j] = 0.f;
  const int start = rowptr[n], end = rowptr[n + 1];
  float mloc[H], dloc[H];
  #pragma unroll
  for (int h = 0; h < H; ++h) { mloc[h] = mb[n * H + h]; dloc[h] = db[n * H + h] + 1e-16f; }
  for (int p = start; p < end; ++p) {
    const int e = elist[p];
    const int s = (e < E) ? src[e] : (e - E);
    float al[H];
    #pragma unroll
    for (int h = 0; h < H; ++h)
      al[h] = __expf(logit[(size_t)e * H + h] - mloc[h]) / dloc[h];
    const float* row = xl + (size_t)s * strideX;
    #pragma unroll
    for (int q = 0; q < NC8; ++q) {
      const int c8 = tid + q * 256;
      if (c8 * 8 < HC) {
        float a = (H == 4) ? ((tid & 128) ? al[2 * q + 1] : al[2 * q]) : al[0];
        f32x4 v0 = *(const f32x4*)(row + c8 * 8);
        f32x4 v1 = *(const f32x4*)(row + c8 * 8 + 4);
        #pragma unroll
        for (int j = 0; j < 4; ++j) { acc[q][j] += a * v0[j]; acc[q][4 + j] += a * v1[j]; }
      }
    }
  }
  #pragma unroll
  for (int q = 0; q < NC8; ++q) {
    const int c8 = tid + q * 256;
    if (c8 * 8 < HC) {
      u16x8 hb, lb;
      #pragma unroll
      for (int j = 0; j < 8; ++j) {
        float v = acc[q][j] + bias[c8 * 8 + j];
        unsigned short h = f2bf(v);
        hb[j] = h; lb[j] = f2bf(v - bf2f(h));
      }
      size_t off = ((size_t)((n >> 7) * KTo + (c8 >> 2)) * 4 + (c8 & 3)) * 1024 + (n & 127) * 8;
      *(u16x8*)&ohi[off] = hb;
      *(u16x8*)&olo[off] = lb;
    }
  }
}

// ---------------- launch ----------------

extern "C" void kernel_launch(void* const* d_in, const int* in_sizes, int n_in,
                              void* d_out, int out_size, void* d_ws, size_t ws_size,
                              hipStream_t stream) {
  const float* x    = (const float*)d_in[0];
  const int*   eidx = (const int*)d_in[1];
  const float* eattr= (const float*)d_in[2];
  const float* W1l  = (const float*)d_in[3];
  const float* b1l  = (const float*)d_in[4];
  const float* W1r  = (const float*)d_in[5];
  const float* b1r  = (const float*)d_in[6];
  const float* W1e  = (const float*)d_in[7];
  const float* att1 = (const float*)d_in[8];
  const float* bias1= (const float*)d_in[9];
  const float* W2l  = (const float*)d_in[10];
  const float* b2l  = (const float*)d_in[11];
  const float* W2r  = (const float*)d_in[12];
  const float* b2r  = (const float*)d_in[13];
  const float* W2e  = (const float*)d_in[14];
  const float* att2 = (const float*)d_in[15];
  const float* bias2= (const float*)d_in[16];
  const float* Wlin = (const float*)d_in[17];
  const float* blin = (const float*)d_in[18];
  float* out = (float*)d_out;

  char* ws = (char*)d_ws;
  const int* srcp = eidx;
  const int* dstp = eidx + E_EDGES;

  auto alignup = [](size_t v) { return (v + 255) & ~(size_t)255; };

  // ---- layout (~325 MB) ----
  const size_t oXHI = 0;                                  // 79 MB (bricks)
  const size_t oXLO = oXHI + (size_t)MP * KP1 * 2;        // 79 MB
  const size_t oXLR = oXLO + (size_t)MP * KP1 * 2;        // xl|xr f32 [5000][8192]: 164 MB
  const size_t oS   = oXLR + (size_t)N_NODES * N1 * 4;
  const size_t oLATTR = alignup(oS);
  const size_t oDEG   = alignup(oLATTR + (size_t)N_NODES * 3 * 4);
  const size_t oEAF   = alignup(oDEG + (size_t)N_NODES * 4);
  const size_t oCNT   = alignup(oEAF + (size_t)EFULL * 3 * 4);
  const size_t oROW   = alignup(oCNT + (size_t)N_NODES * 4);
  const size_t oFILL  = alignup(oROW + (size_t)(N_NODES + 1) * 4);
  const size_t oELIST = alignup(oFILL + (size_t)N_NODES * 4);
  const size_t oLOGIT = alignup(oELIST + (size_t)EFULL * 4);
  const size_t oMB    = alignup(oLOGIT + (size_t)EFULL * 4 * 4);
  const size_t oDB    = alignup(oMB + (size_t)N_NODES * 4 * 4);
  const size_t oEND   = alignup(oDB + (size_t)N_NODES * 4 * 4);
  if (ws_size < oEND) return;

  // overlays
  const size_t oH1HI = oXHI;                           // bricks [MP][4096]: 42 MB (in 79)
  const size_t oH1LO = oXLO;                           // 42 MB (in 79)
  const size_t oXLR2 = oXLR;                           // f32 [5000][2048]: 41 MB (in 164)
  const size_t oH2HI = oXLR + 64ull * 1024 * 1024;     // bricks [MP][1024]: 10.5 MB
  const size_t oH2LO = oXLR + 80ull * 1024 * 1024;     // 10.5 MB

  unsigned short* XHI  = (unsigned short*)(ws + oXHI);
  unsigned short* XLO  = (unsigned short*)(ws + oXLO);
  float*          XLR  = (float*)(ws + oXLR);
  float*          LATTR= (float*)(ws + oLATTR);
  float*          DEG  = (float*)(ws + oDEG);
  float*          EAF  = (float*)(ws + oEAF);
  int*            CNT  = (int*)(ws + oCNT);
  int*            ROWP = (int*)(ws + oROW);
  int*            FILLC= (int*)(ws + oFILL);
  int*            ELIST= (int*)(ws + oELIST);
  float*          LOGIT= (float*)(ws + oLOGIT);
  float*          MB   = (float*)(ws + oMB);
  float*          DB   = (float*)(ws + oDB);
  unsigned short* H1HI = (unsigned short*)(ws + oH1HI);
  unsigned short* H1LO = (unsigned short*)(ws + oH1LO);
  float*          XLR2 = (float*)(ws + oXLR2);
  unsigned short* H2HI = (unsigned short*)(ws + oH2HI);
  unsigned short* H2LO = (unsigned short*)(ws + oH2LO);

  hipMemsetAsync(ws + oDEG,   0, (size_t)N_NODES * 4, stream);
  hipMemsetAsync(ws + oLATTR, 0, (size_t)N_NODES * 3 * 4, stream);
  hipMemsetAsync(ws + oCNT,   0, (size_t)N_NODES * 4, stream);
  hipMemsetAsync(ws + oFILL,  0, (size_t)N_NODES * 4, stream);

  const int gE  = (E_EDGES + 255) / 256;
  const int gEF = (EFULL + 255) / 256;
  const int gN  = (N_NODES + 255) / 256;

  // ---- graph structure ----
  k_deg<<<gE, 256, 0, stream>>>(dstp, eattr, DEG, LATTR, E_EDGES);
  k_lattr_fin<<<gN, 256, 0, stream>>>(LATTR, DEG, N_NODES);
  k_eafull<<<gEF, 256, 0, stream>>>(eattr, LATTR, EAF, E_EDGES, N_NODES);
  k_count<<<gEF, 256, 0, stream>>>(dstp, CNT, E_EDGES, N_NODES);
  k_scan<<<1, 64, 0, stream>>>(CNT, ROWP, N_NODES);
  k_fill<<<gEF, 256, 0, stream>>>(dstp, ROWP, FILLC, ELIST, E_EDGES, N_NODES);

  // ---- layer 1 ----
  k_split_x<<<MP * (KP1 / 8) / 256, 256, 0, stream>>>(x, XHI, XLO);
  k_gemm_bs<<<64 * (MP / 128), 256, 0, stream>>>(
      XHI, XLO, W1l, W1r, HC1, 32,
      XLR, b1l, b1r, HC1, N_NODES, N1, KT1, F_IN, MP / 128);

  k_logit<4, 16><<<EFULL, 256, 0, stream>>>(XLR, XLR + HC1, N1, EAF, W1e, att1, srcp, dstp, E_EDGES, LOGIT);
  k_stats<4><<<N_NODES, 64, 0, stream>>>(LOGIT, ROWP, ELIST, MB, DB);
  // zero H1 bricks (pad rows 5000..5119 must be 0 for GEMM2)
  hipMemsetAsync(ws + oH1HI, 0, (size_t)MP * HC1 * 2, stream);
  hipMemsetAsync(ws + oH1LO, 0, (size_t)MP * HC1 * 2, stream);
  k_agg<4, 2, HC1 / 32><<<N_NODES, 256, 0, stream>>>(
      XLR, N1, ROWP, ELIST, srcp, LOGIT, MB, DB, bias1, H1HI, H1LO, E_EDGES);

  // ---- layer 2 ----
  k_gemm_bs<<<16 * (MP / 128), 256, 0, stream>>>(
      H1HI, H1LO, W2l, W2r, HC2, 8,
      XLR2, b2l, b2r, HC2, N_NODES, N2, HC1 / 32, HC1, MP / 128);

  k_logit<1, 4><<<EFULL, 256, 0, stream>>>(XLR2, XLR2 + HC2, N2, EAF, W2e, att2, srcp, dstp, E_EDGES, LOGIT);
  k_stats<1><<<N_NODES, 64, 0, stream>>>(LOGIT, ROWP, ELIST, MB, DB);
  hipMemsetAsync(ws + oH2HI, 0, (size_t)MP * HC2 * 2, stream);
  hipMemsetAsync(ws + oH2LO, 0, (size_t)MP * HC2 * 2, stream);
  k_agg<1, 1, HC2 / 32><<<N_NODES, 256, 0, stream>>>(
      XLR2, N2, ROWP, ELIST, srcp, LOGIT, MB, DB, bias2, H2HI, H2LO, E_EDGES);

  // ---- final linear ----
  k_gemm_bs<<<1 * (MP / 128), 256, 0, stream>>>(
      H2HI, H2LO, Wlin, Wlin, NOUT, 1,
      out, blin, blin, NOUT, N_NODES, NOUT, HC2 / 32, HC2, MP / 128);
}